// Round 5
// baseline (938.996 us; speedup 1.0000x reference)
//
#include <hip/hip_runtime.h>
#include <hip/hip_bf16.h>
#include <hip/hip_fp16.h>

// B=2 H=16 S=2048 DK=128, fp32 in/out. out = [context (B,H,S,DK) | attn (B,H,S,S)]
// Strategy: prep kernel writes fp16 K (row-major) + fp16 V^T (d-major) to d_ws
// (needs 32MB scratch). Main kernel is BARRIER-FREE: QK/PV operand fragments are
// direct 16B global loads from the L2-resident fp16 copies; only LDS use is the
// per-wave P transpose buffer. M stream register-prefetched 4 tiles deep.
constexpr int Bc = 2, Hc = 16, Sc = 2048, Dc = 128;
constexpr int BQ = 64;          // q-rows per block (4 waves x 16)
constexpr int KT = 32;          // k-cols per iteration
constexpr int NT = Sc / KT;     // 64
constexpr size_t SK = (size_t)Sc * Dc;   // 262144 elems per head (K or V)
constexpr float SCALE = 0.08838834764831844f;  // 1/sqrt(128)

typedef _Float16 half8 __attribute__((ext_vector_type(8)));
typedef float float4v __attribute__((ext_vector_type(4)));

#define LGKM0() { asm volatile("s_waitcnt lgkmcnt(0)" ::: "memory"); \
                  __builtin_amdgcn_sched_barrier(0); }

// ---------------- prep: Kh = fp16(K); Vt = fp16(V^T) ----------------
__global__ __launch_bounds__(256, 2)
void prep_kernel(const float* __restrict__ K, const float* __restrict__ V,
                 _Float16* __restrict__ Kh, _Float16* __restrict__ Vt)
{
    __shared__ _Float16 T[128 * 136];   // [d][k] tile, pad 8 halves
    const int b = blockIdx.x, t = threadIdx.x;
    if (b < 512) {
        // transpose one 128(k) x 128(d) tile of V -> Vt[h][d][k]
        const int h = b >> 4, k0 = (b & 15) * 128;
        const float* Vp = V + (size_t)h * SK + (size_t)k0 * Dc;
        const int krow = t >> 1, dp = (t & 1) * 64;
        #pragma unroll
        for (int c = 0; c < 16; ++c) {
            float4v f = *(const float4v*)&Vp[krow * Dc + dp + c * 4];
            #pragma unroll
            for (int i = 0; i < 4; ++i)
                T[(dp + c * 4 + i) * 136 + krow] = (_Float16)f[i];
        }
        __syncthreads();
        const int drow = t >> 1, kp = (t & 1) * 64;
        _Float16* out = Vt + (size_t)h * SK + (size_t)drow * Sc + k0 + kp;
        #pragma unroll
        for (int c = 0; c < 8; ++c)
            *(half8*)(out + c * 8) = *(const half8*)&T[drow * 136 + kp + c * 8];
    } else {
        // straight fp32->fp16 cast of K
        const size_t base = ((size_t)(b - 512) * 256 + t) * 64;
        #pragma unroll
        for (int c = 0; c < 8; ++c) {
            float4v f0 = *(const float4v*)&K[base + c * 8];
            float4v f1 = *(const float4v*)&K[base + c * 8 + 4];
            half8 h8;
            #pragma unroll
            for (int i = 0; i < 4; ++i) { h8[i] = (_Float16)f0[i]; h8[4 + i] = (_Float16)f1[i]; }
            *(half8*)&Kh[base + c * 8] = h8;
        }
    }
}

// ---------------- main: barrier-free fused attention ----------------
__global__ __launch_bounds__(256, 3)
void sdpa_kernel(const float* __restrict__ Q, const _Float16* __restrict__ Kh,
                 const _Float16* __restrict__ Vt, const float* __restrict__ M,
                 float* __restrict__ outC, float* __restrict__ outA)
{
    __shared__ __align__(16) float Pl[4][16 * 36];  // per-wave P transpose buf

    int bid = blockIdx.x;
    bid = (bid & 7) * 128 + (bid >> 3);   // XCD swizzle (1024 % 8 == 0, bijective)
    const int head = bid >> 5;
    const int q0   = (bid & 31) * BQ;

    const int tid  = threadIdx.x;
    const int wv   = tid >> 6;
    const int lane = tid & 63;
    const int g    = lane >> 4;
    const int c16  = lane & 15;
    const int qrow0 = q0 + wv * 16;

    const float*    Qh  = Q  + (size_t)head * SK;
    const _Float16* Khh = Kh + (size_t)head * SK;
    const _Float16* Vth = Vt + (size_t)head * SK;
    const float*    Mh  = M  + (size_t)head * Sc * Sc;
    float* Ch = outC + (size_t)head * SK;
    float* Ah = outA + (size_t)head * Sc * Sc;

    // ---- Q A-fragments (fp16): rows qrow0+c16, d-elems c*32 + g*8 + j ----
    half8 aq[4];
    {
        const float* qp = Qh + (size_t)(qrow0 + c16) * Dc + g * 8;
        #pragma unroll
        for (int c = 0; c < 4; ++c) {
            float4v f0 = *(const float4v*)(qp + c * 32);
            float4v f1 = *(const float4v*)(qp + c * 32 + 4);
            half8 h;
            #pragma unroll
            for (int j = 0; j < 4; ++j) { h[j] = (_Float16)f0[j]; h[4 + j] = (_Float16)f1[j]; }
            aq[c] = h;
        }
    }

    // QK for one 32-col tile: B-frags direct from L2-resident fp16 K
#define QK_TILE(KB, ACCS) \
    _Pragma("unroll") \
    for (int sub = 0; sub < 2; ++sub) { \
        const _Float16* rp = Khh + (size_t)((KB) + sub * 16 + c16) * Dc + g * 8; \
        _Pragma("unroll") \
        for (int c = 0; c < 4; ++c) { \
            half8 bk = *(const half8*)(rp + c * 32); \
            ACCS[sub] = __builtin_amdgcn_mfma_f32_16x16x32_f16(aq[c], bk, ACCS[sub], 0, 0, 0); \
        } \
    }

    // ================= Pass A: row sums of exp(scores) — no LDS, no barriers ==
    float psum[4] = {0.f, 0.f, 0.f, 0.f};
    for (int kb = 0; kb < Sc; kb += KT) {
        float4v accS[2] = {{0,0,0,0},{0,0,0,0}};
        QK_TILE(kb, accS)
        #pragma unroll
        for (int sub = 0; sub < 2; ++sub)
            #pragma unroll
            for (int r = 0; r < 4; ++r)
                psum[r] += __expf(accS[sub][r] * SCALE);
    }
    #pragma unroll
    for (int m = 1; m < 16; m <<= 1)
        #pragma unroll
        for (int r = 0; r < 4; ++r)
            psum[r] += __shfl_xor(psum[r], m, 64);
    float invl[4];
    #pragma unroll
    for (int r = 0; r < 4; ++r) invl[r] = 1.0f / psum[r];

    // ================= Pass B ================================================
    float4v accC[8];
    #pragma unroll
    for (int d = 0; d < 8; ++d) accC[d] = (float4v){0, 0, 0, 0};

    float* pw = &Pl[wv][0];
    const float* mrow = Mh + (size_t)(qrow0 + c16) * Sc + g * 8;

    // M register prefetch: 4 named tile slots (2 x float4v each)
    float4v mA0, mA1, mB0, mB1, mC0, mC1, mD0, mD1;
#define LOADM(T, M0, M1) { const float* mp = mrow + (size_t)(T) * KT; \
    M0 = *(const float4v*)mp; M1 = *(const float4v*)(mp + 4); }

    LOADM(0, mA0, mA1)
    LOADM(1, mB0, mB1)
    LOADM(2, mC0, mC1)
    LOADM(3, mD0, mD1)

#define BODY(T, M0, M1) { \
    const int kb = (T) * KT; \
    float4v accS[2] = {{0,0,0,0},{0,0,0,0}}; \
    QK_TILE(kb, accS) \
    _Pragma("unroll") \
    for (int sub = 0; sub < 2; ++sub) \
        _Pragma("unroll") \
        for (int r = 0; r < 4; ++r) { \
            float p = __expf(accS[sub][r] * SCALE) * invl[r]; \
            pw[(g * 4 + r) * 36 + sub * 16 + c16] = p; \
        } \
    LGKM0(); \
    float4v p0 = *(const float4v*)&pw[c16 * 36 + g * 8]; \
    float4v p1 = *(const float4v*)&pw[c16 * 36 + g * 8 + 4]; \
    float* as_ = &Ah[(size_t)(qrow0 + c16) * Sc + kb + g * 8]; \
    *(float4v*)as_       = p0; \
    *(float4v*)(as_ + 4) = p1; \
    half8 ap; \
    _Pragma("unroll") \
    for (int j = 0; j < 4; ++j) { \
        ap[j]     = (_Float16)(0.7f * p0[j] + 0.3f * M0[j]); \
        ap[4 + j] = (_Float16)(0.7f * p1[j] + 0.3f * M1[j]); \
    } \
    if ((T) + 4 < NT) LOADM((T) + 4, M0, M1) \
    _Pragma("unroll") \
    for (int d = 0; d < 8; ++d) { \
        half8 bv = *(const half8*)&Vth[(size_t)(d * 16 + c16) * Sc + kb + g * 8]; \
        accC[d] = __builtin_amdgcn_mfma_f32_16x16x32_f16(ap, bv, accC[d], 0, 0, 0); \
    } }

    for (int tb = 0; tb < NT; tb += 4) {
        BODY(tb + 0, mA0, mA1)
        BODY(tb + 1, mB0, mB1)
        BODY(tb + 2, mC0, mC1)
        BODY(tb + 3, mD0, mD1)
    }

    // ================= epilogue: context (blend already applied) =============
    #pragma unroll
    for (int d = 0; d < 8; ++d)
        #pragma unroll
        for (int r = 0; r < 4; ++r)
            Ch[(size_t)(qrow0 + g * 4 + r) * Dc + d * 16 + c16] = accC[d][r];
}

extern "C" void kernel_launch(void* const* d_in, const int* in_sizes, int n_in,
                              void* d_out, int out_size, void* d_ws, size_t ws_size,
                              hipStream_t stream) {
    const float* Q = (const float*)d_in[0];
    const float* K = (const float*)d_in[1];
    const float* V = (const float*)d_in[2];
    const float* M = (const float*)d_in[4];   // d_in[3] = attn_mask (unused)
    float* outC = (float*)d_out;
    float* outA = outC + (size_t)Bc * Hc * SK;

    _Float16* Kh = (_Float16*)d_ws;                 // 16MB
    _Float16* Vt = Kh + (size_t)8 * 1024 * 1024;    // +16MB (ws needs 32MB)

    prep_kernel<<<dim3(1024), dim3(256), 0, stream>>>(K, V, Kh, Vt);
    sdpa_kernel<<<dim3(1024), dim3(256), 0, stream>>>(Q, Kh, Vt, M, outC, outA);
}

// Round 6
// 602.292 us; speedup vs baseline: 1.5590x; 1.5590x over previous
//
#include <hip/hip_runtime.h>
#include <hip/hip_bf16.h>
#include <hip/hip_fp16.h>

// B=2 H=16 S=2048 DK=128, fp32 in/out. out = [context (B,H,S,DK) | attn (B,H,S,S)]
// R6 = R4 structure (reg-prefetch + LDS dbuf + 1 raw barrier/iter) with fp16
// P-transpose buffer (5KB) -> LDS 37888B -> 4 blocks/CU occupancy.
constexpr int Bc = 2, Hc = 16, Sc = 2048, Dc = 128;
constexpr int BQ = 64;   // q-rows per block (4 waves x 16)
constexpr int KT = 32;   // k-cols per iteration
constexpr int NT = Sc / KT;  // 64
constexpr int PSTRIDE = 40;  // halves per P-row (80B, 16B-aligned, conflict-benign)
constexpr float SCALE = 0.08838834764831844f;  // 1/sqrt(128)

typedef _Float16 half8 __attribute__((ext_vector_type(8)));
typedef _Float16 half4v __attribute__((ext_vector_type(4)));
typedef float float4v __attribute__((ext_vector_type(4)));

// raw barrier: NO vmcnt drain (prefetch loads stay in flight across it)
#define SBAR() { __builtin_amdgcn_sched_barrier(0); \
                 __builtin_amdgcn_s_barrier(); \
                 __builtin_amdgcn_sched_barrier(0); }
#define LGKM0() { asm volatile("s_waitcnt lgkmcnt(0)" ::: "memory"); \
                  __builtin_amdgcn_sched_barrier(0); }

__global__ __launch_bounds__(256, 4)
void sdpa_kernel(const float* __restrict__ Q, const float* __restrict__ K,
                 const float* __restrict__ V, const float* __restrict__ M,
                 float* __restrict__ outC, float* __restrict__ outA)
{
    __shared__ __align__(16) _Float16 Kl[2][KT * Dc];       // 2x8KB, XOR-swizzled rows
    __shared__ __align__(16) _Float16 Vl[2][KT * Dc];       // 2x8KB, tr-subtiled
    __shared__ __align__(16) _Float16 Pl[4][16 * PSTRIDE];  // 5KB per-wave P buf (fp16)

    int bid = blockIdx.x;
    bid = (bid & 7) * 128 + (bid >> 3);   // XCD swizzle (1024 % 8 == 0, bijective)
    const int head = bid >> 5;
    const int q0   = (bid & 31) * BQ;

    const int tid  = threadIdx.x;
    const int wv   = tid >> 6;
    const int lane = tid & 63;
    const int g    = lane >> 4;
    const int c16  = lane & 15;
    const int qrow0 = q0 + wv * 16;

    const float* Qh = Q + (size_t)head * Sc * Dc;
    const float* Kh = K + (size_t)head * Sc * Dc;
    const float* Vh = V + (size_t)head * Sc * Dc;
    const float* Mh = M + (size_t)head * Sc * Sc;
    float* Ch = outC + (size_t)head * Sc * Dc;
    float* Ah = outA + (size_t)head * Sc * Sc;

    // ---- Q A-fragments (fp16): rows qrow0+c16, k-elems c*32 + g*8 + j ----
    half8 aq[4];
    {
        const float* qp = Qh + (size_t)(qrow0 + c16) * Dc + g * 8;
        #pragma unroll
        for (int c = 0; c < 4; ++c) {
            float4v f0 = *(const float4v*)(qp + c * 32);
            float4v f1 = *(const float4v*)(qp + c * 32 + 4);
            half8 h;
            #pragma unroll
            for (int j = 0; j < 4; ++j) { h[j] = (_Float16)f0[j]; h[4 + j] = (_Float16)f1[j]; }
            aq[c] = h;
        }
    }

    // staging coords: thread -> K/V row kr, d-chunk dc0
    const int kr  = tid >> 3;
    const int dc0 = (tid & 7) * 16;

    float4v kf[4], vf[4];          // prefetch registers (live across one iteration)

    auto loadK = [&](int t) {
        const float* kp = Kh + (size_t)(t * KT + kr) * Dc + dc0;
        #pragma unroll
        for (int i = 0; i < 4; ++i) kf[i] = *(const float4v*)(kp + 4 * i);
    };
    auto loadV = [&](int t) {
        const float* vp = Vh + (size_t)(t * KT + kr) * Dc + dc0;
        #pragma unroll
        for (int i = 0; i < 4; ++i) vf[i] = *(const float4v*)(vp + 4 * i);
    };
    auto writeK = [&](int buf) {
        half8 h0, h1;
        #pragma unroll
        for (int j = 0; j < 4; ++j) {
            h0[j] = (_Float16)kf[0][j]; h0[4 + j] = (_Float16)kf[1][j];
            h1[j] = (_Float16)kf[2][j]; h1[4 + j] = (_Float16)kf[3][j];
        }
        const int sw = (kr & 7) << 3;
        *(half8*)&Kl[buf][kr * Dc + ((dc0    ) ^ sw)] = h0;
        *(half8*)&Kl[buf][kr * Dc + ((dc0 + 8) ^ sw)] = h1;
    };
    auto writeV = [&](int buf) {
        half8 h0, h1;
        #pragma unroll
        for (int j = 0; j < 4; ++j) {
            h0[j] = (_Float16)vf[0][j]; h0[4 + j] = (_Float16)vf[1][j];
            h1[j] = (_Float16)vf[2][j]; h1[4 + j] = (_Float16)vf[3][j];
        }
        const int kq = kr >> 2;
        const int sub = ((tid & 7) * 2 + (kq & 1)) * 4 + (kq >> 1);
        const int base = sub * 64 + (kr & 3) * 16;
        *(half8*)&Vl[buf][base]     = h0;
        *(half8*)&Vl[buf][base + 8] = h1;
    };

    auto qk = [&](int buf, float4v accS[2]) {
        #pragma unroll
        for (int sub = 0; sub < 2; ++sub) {
            const int krow = sub * 16 + c16;
            const _Float16* rp = &Kl[buf][krow * Dc];
            const int sw = (krow & 7) << 3;
            #pragma unroll
            for (int c = 0; c < 4; ++c) {
                half8 bk = *(const half8*)&rp[(c * 32 + g * 8) ^ sw];
                accS[sub] = __builtin_amdgcn_mfma_f32_16x16x32_f16(aq[c], bk, accS[sub], 0, 0, 0);
            }
        }
    };

    // ================= Pass A: row sums of exp(scores) =================
    float psum[4] = {0.f, 0.f, 0.f, 0.f};
    loadK(0);
    writeK(0);
    loadK(1);
    LGKM0(); SBAR();
    for (int t = 0; t < NT; ++t) {
        const int cur = t & 1;
        float4v accS[2] = {{0,0,0,0},{0,0,0,0}};
        qk(cur, accS);
        #pragma unroll
        for (int sub = 0; sub < 2; ++sub)
            #pragma unroll
            for (int r = 0; r < 4; ++r)
                psum[r] += __expf(accS[sub][r] * SCALE);
        if (t + 1 < NT) {
            writeK(cur ^ 1);
            if (t + 2 < NT) loadK(t + 2);
        }
        LGKM0(); SBAR();
    }

    #pragma unroll
    for (int m = 1; m < 16; m <<= 1)
        #pragma unroll
        for (int r = 0; r < 4; ++r)
            psum[r] += __shfl_xor(psum[r], m, 64);
    float invl[4];
    #pragma unroll
    for (int r = 0; r < 4; ++r) invl[r] = 1.0f / psum[r];

    // ================= Pass B =================
    float4v accC[8];
    #pragma unroll
    for (int d = 0; d < 8; ++d) accC[d] = (float4v){0, 0, 0, 0};

    float4v m0, m1;
    auto loadM = [&](int t) {
        const float* mp = Mh + (size_t)(qrow0 + c16) * Sc + t * KT + g * 8;
        m0 = *(const float4v*)mp;
        m1 = *(const float4v*)(mp + 4);
    };

    // prologue: fill buf0, prefetch tile1 + M0
    loadK(0); loadV(0);
    writeK(0); writeV(0);
    loadK(1); loadV(1);
    loadM(0);
    LGKM0(); SBAR();

    const unsigned int vbase0 = (unsigned int)(uintptr_t)(&Vl[0][0]);
    _Float16* pw = &Pl[wv][0];

    // PV tr-read pipeline: 4 static reg slots (mod-4), counted lgkm waits
    half4v trA[4], trB[4];
#define TRI(D) { unsigned int a_ = vb + (D) * 1024 + lane * 8; \
    asm volatile("ds_read_b64_tr_b16 %0, %2\n\t" \
                 "ds_read_b64_tr_b16 %1, %2 offset:512" \
                 : "=&v"(trA[(D) & 3]), "=&v"(trB[(D) & 3]) : "v"(a_)); }
#define PVM(D, N) { \
    asm volatile("s_waitcnt lgkmcnt(" #N ")" ::: "memory"); \
    __builtin_amdgcn_sched_barrier(0); \
    half8 bv; \
    for (int j = 0; j < 4; ++j) { bv[j] = trA[(D) & 3][j]; bv[4 + j] = trB[(D) & 3][j]; } \
    accC[D] = __builtin_amdgcn_mfma_f32_16x16x32_f16(ap, bv, accC[D], 0, 0, 0); }

    for (int t = 0; t < NT; ++t) {
        const int cur = t & 1;

        float4v accS[2] = {{0,0,0,0},{0,0,0,0}};
        qk(cur, accS);

        // normalized p -> per-wave fp16 P buffer (C layout write)
        #pragma unroll
        for (int sub = 0; sub < 2; ++sub)
            #pragma unroll
            for (int r = 0; r < 4; ++r) {
                float p = __expf(accS[sub][r] * SCALE) * invl[r];
                pw[(g * 4 + r) * PSTRIDE + sub * 16 + c16] = (_Float16)p;
            }
        LGKM0();

        // read back in A layout: row c16, halves g*8..+7 (16B aligned)
        half8 ph = *(const half8*)&pw[c16 * PSTRIDE + g * 8];
        float pf[8];
        #pragma unroll
        for (int j = 0; j < 8; ++j) pf[j] = (float)ph[j];

        // vectorized attn store (never waited on — no vmcnt drain in loop)
        float* as_ = &Ah[(size_t)(qrow0 + c16) * Sc + t * KT + g * 8];
        *(float4v*)as_       = (float4v){pf[0], pf[1], pf[2], pf[3]};
        *(float4v*)(as_ + 4) = (float4v){pf[4], pf[5], pf[6], pf[7]};

        // blend with prefetched M, convert to fp16 A-fragment
        half8 ap;
        #pragma unroll
        for (int j = 0; j < 4; ++j) {
            ap[j]     = (_Float16)(0.7f * pf[j]     + 0.3f * m0[j]);
            ap[4 + j] = (_Float16)(0.7f * pf[4 + j] + 0.3f * m1[j]);
        }
        if (t + 1 < NT) loadM(t + 1);

        // ---- PV: tr-reads pipelined 3-pairs-deep, counted lgkm ----
        LGKM0();   // zero the lgkm baseline for counted waits
        const unsigned int vb = vbase0 + (unsigned int)(cur * (KT * Dc * 2));
        TRI(0) TRI(1)
        TRI(2) PVM(0, 4)
        TRI(3) PVM(1, 4)
        TRI(4) PVM(2, 4)
        TRI(5) PVM(3, 4)
        TRI(6) PVM(4, 4)
        TRI(7) PVM(5, 4)
        PVM(6, 2)
        PVM(7, 0)

        // stage next tile into the other buffer; issue loads for t+2
        if (t + 1 < NT) {
            writeK(cur ^ 1); writeV(cur ^ 1);
            if (t + 2 < NT) { loadK(t + 2); loadV(t + 2); }
        }
        LGKM0(); SBAR();
    }

    // ================= epilogue: context =================
    #pragma unroll
    for (int d = 0; d < 8; ++d)
        #pragma unroll
        for (int r = 0; r < 4; ++r)
            Ch[(size_t)(qrow0 + g * 4 + r) * Dc + d * 16 + c16] = accC[d][r];
}

extern "C" void kernel_launch(void* const* d_in, const int* in_sizes, int n_in,
                              void* d_out, int out_size, void* d_ws, size_t ws_size,
                              hipStream_t stream) {
    const float* Q = (const float*)d_in[0];
    const float* K = (const float*)d_in[1];
    const float* V = (const float*)d_in[2];
    const float* M = (const float*)d_in[4];   // d_in[3] = attn_mask (unused)
    float* outC = (float*)d_out;
    float* outA = outC + (size_t)Bc * Hc * Sc * Dc;

    const int grid = Bc * Hc * (Sc / BQ);  // 1024
    sdpa_kernel<<<dim3(grid), dim3(256), 0, stream>>>(Q, K, V, M, outC, outA);
}

// Round 7
// 447.004 us; speedup vs baseline: 2.1006x; 1.3474x over previous
//
#include <hip/hip_runtime.h>
#include <hip/hip_bf16.h>
#include <hip/hip_fp16.h>

// B=2 H=16 S=2048 DK=128, fp32 in/out. out = [context (B,H,S,DK) | attn (B,H,S,S)]
// R7 = R4 structure (reg-prefetch + LDS dbuf + 1 raw barrier/iter)
//      + fp16 P buffer (LDS 37888 -> 4 blocks/CU)
//      + __launch_bounds__(256,3) (VGPR cap ~170: no spill squeeze, unlike R6's (256,4))
constexpr int Bc = 2, Hc = 16, Sc = 2048, Dc = 128;
constexpr int BQ = 64;   // q-rows per block (4 waves x 16)
constexpr int KT = 32;   // k-cols per iteration
constexpr int NT = Sc / KT;  // 64
constexpr int PSTRIDE = 40;  // halves per P-row (80B, 16B-aligned)
constexpr float SCALE = 0.08838834764831844f;  // 1/sqrt(128)

typedef _Float16 half8 __attribute__((ext_vector_type(8)));
typedef _Float16 half4v __attribute__((ext_vector_type(4)));
typedef float float4v __attribute__((ext_vector_type(4)));

// raw barrier: NO vmcnt drain (prefetch loads stay in flight across it)
#define SBAR() { __builtin_amdgcn_sched_barrier(0); \
                 __builtin_amdgcn_s_barrier(); \
                 __builtin_amdgcn_sched_barrier(0); }
#define LGKM0() { asm volatile("s_waitcnt lgkmcnt(0)" ::: "memory"); \
                  __builtin_amdgcn_sched_barrier(0); }

__global__ __launch_bounds__(256, 3)
void sdpa_kernel(const float* __restrict__ Q, const float* __restrict__ K,
                 const float* __restrict__ V, const float* __restrict__ M,
                 float* __restrict__ outC, float* __restrict__ outA)
{
    __shared__ __align__(16) _Float16 Kl[2][KT * Dc];       // 2x8KB, XOR-swizzled rows
    __shared__ __align__(16) _Float16 Vl[2][KT * Dc];       // 2x8KB, tr-subtiled
    __shared__ __align__(16) _Float16 Pl[4][16 * PSTRIDE];  // 5KB per-wave P buf (fp16)

    int bid = blockIdx.x;
    bid = (bid & 7) * 128 + (bid >> 3);   // XCD swizzle (1024 % 8 == 0, bijective)
    const int head = bid >> 5;
    const int q0   = (bid & 31) * BQ;

    const int tid  = threadIdx.x;
    const int wv   = tid >> 6;
    const int lane = tid & 63;
    const int g    = lane >> 4;
    const int c16  = lane & 15;
    const int qrow0 = q0 + wv * 16;

    const float* Qh = Q + (size_t)head * Sc * Dc;
    const float* Kh = K + (size_t)head * Sc * Dc;
    const float* Vh = V + (size_t)head * Sc * Dc;
    const float* Mh = M + (size_t)head * Sc * Sc;
    float* Ch = outC + (size_t)head * Sc * Dc;
    float* Ah = outA + (size_t)head * Sc * Sc;

    // ---- Q A-fragments (fp16): rows qrow0+c16, k-elems c*32 + g*8 + j ----
    half8 aq[4];
    {
        const float* qp = Qh + (size_t)(qrow0 + c16) * Dc + g * 8;
        #pragma unroll
        for (int c = 0; c < 4; ++c) {
            float4v f0 = *(const float4v*)(qp + c * 32);
            float4v f1 = *(const float4v*)(qp + c * 32 + 4);
            half8 h;
            #pragma unroll
            for (int j = 0; j < 4; ++j) { h[j] = (_Float16)f0[j]; h[4 + j] = (_Float16)f1[j]; }
            aq[c] = h;
        }
    }

    // staging coords: thread -> K/V row kr, d-chunk dc0
    const int kr  = tid >> 3;
    const int dc0 = (tid & 7) * 16;

    float4v kf[4], vf[4];          // prefetch registers (live across one iteration)

    auto loadK = [&](int t) {
        const float* kp = Kh + (size_t)(t * KT + kr) * Dc + dc0;
        #pragma unroll
        for (int i = 0; i < 4; ++i) kf[i] = *(const float4v*)(kp + 4 * i);
    };
    auto loadV = [&](int t) {
        const float* vp = Vh + (size_t)(t * KT + kr) * Dc + dc0;
        #pragma unroll
        for (int i = 0; i < 4; ++i) vf[i] = *(const float4v*)(vp + 4 * i);
    };
    auto writeK = [&](int buf) {
        half8 h0, h1;
        #pragma unroll
        for (int j = 0; j < 4; ++j) {
            h0[j] = (_Float16)kf[0][j]; h0[4 + j] = (_Float16)kf[1][j];
            h1[j] = (_Float16)kf[2][j]; h1[4 + j] = (_Float16)kf[3][j];
        }
        const int sw = (kr & 7) << 3;
        *(half8*)&Kl[buf][kr * Dc + ((dc0    ) ^ sw)] = h0;
        *(half8*)&Kl[buf][kr * Dc + ((dc0 + 8) ^ sw)] = h1;
    };
    auto writeV = [&](int buf) {
        half8 h0, h1;
        #pragma unroll
        for (int j = 0; j < 4; ++j) {
            h0[j] = (_Float16)vf[0][j]; h0[4 + j] = (_Float16)vf[1][j];
            h1[j] = (_Float16)vf[2][j]; h1[4 + j] = (_Float16)vf[3][j];
        }
        const int kq = kr >> 2;
        const int sub = ((tid & 7) * 2 + (kq & 1)) * 4 + (kq >> 1);
        const int base = sub * 64 + (kr & 3) * 16;
        *(half8*)&Vl[buf][base]     = h0;
        *(half8*)&Vl[buf][base + 8] = h1;
    };

    auto qk = [&](int buf, float4v accS[2]) {
        #pragma unroll
        for (int sub = 0; sub < 2; ++sub) {
            const int krow = sub * 16 + c16;
            const _Float16* rp = &Kl[buf][krow * Dc];
            const int sw = (krow & 7) << 3;
            #pragma unroll
            for (int c = 0; c < 4; ++c) {
                half8 bk = *(const half8*)&rp[(c * 32 + g * 8) ^ sw];
                accS[sub] = __builtin_amdgcn_mfma_f32_16x16x32_f16(aq[c], bk, accS[sub], 0, 0, 0);
            }
        }
    };

    // ================= Pass A: row sums of exp(scores) =================
    float psum[4] = {0.f, 0.f, 0.f, 0.f};
    loadK(0);
    writeK(0);
    loadK(1);
    LGKM0(); SBAR();
    for (int t = 0; t < NT; ++t) {
        const int cur = t & 1;
        float4v accS[2] = {{0,0,0,0},{0,0,0,0}};
        qk(cur, accS);
        #pragma unroll
        for (int sub = 0; sub < 2; ++sub)
            #pragma unroll
            for (int r = 0; r < 4; ++r)
                psum[r] += __expf(accS[sub][r] * SCALE);
        if (t + 1 < NT) {
            writeK(cur ^ 1);
            if (t + 2 < NT) loadK(t + 2);
        }
        LGKM0(); SBAR();
    }

    #pragma unroll
    for (int m = 1; m < 16; m <<= 1)
        #pragma unroll
        for (int r = 0; r < 4; ++r)
            psum[r] += __shfl_xor(psum[r], m, 64);
    float invl[4];
    #pragma unroll
    for (int r = 0; r < 4; ++r) invl[r] = 1.0f / psum[r];

    // ================= Pass B =================
    float4v accC[8];
    #pragma unroll
    for (int d = 0; d < 8; ++d) accC[d] = (float4v){0, 0, 0, 0};

    float4v m0, m1;
    auto loadM = [&](int t) {
        const float* mp = Mh + (size_t)(qrow0 + c16) * Sc + t * KT + g * 8;
        m0 = *(const float4v*)mp;
        m1 = *(const float4v*)(mp + 4);
    };

    // prologue: fill buf0, prefetch tile1 + M0
    loadK(0); loadV(0);
    writeK(0); writeV(0);
    loadK(1); loadV(1);
    loadM(0);
    LGKM0(); SBAR();

    const unsigned int vbase0 = (unsigned int)(uintptr_t)(&Vl[0][0]);
    _Float16* pw = &Pl[wv][0];

    // PV tr-read pipeline: 4 static reg slots (mod-4), counted lgkm waits
    half4v trA[4], trB[4];
#define TRI(D) { unsigned int a_ = vb + (D) * 1024 + lane * 8; \
    asm volatile("ds_read_b64_tr_b16 %0, %2\n\t" \
                 "ds_read_b64_tr_b16 %1, %2 offset:512" \
                 : "=&v"(trA[(D) & 3]), "=&v"(trB[(D) & 3]) : "v"(a_)); }
#define PVM(D, N) { \
    asm volatile("s_waitcnt lgkmcnt(" #N ")" ::: "memory"); \
    __builtin_amdgcn_sched_barrier(0); \
    half8 bv; \
    for (int j = 0; j < 4; ++j) { bv[j] = trA[(D) & 3][j]; bv[4 + j] = trB[(D) & 3][j]; } \
    accC[D] = __builtin_amdgcn_mfma_f32_16x16x32_f16(ap, bv, accC[D], 0, 0, 0); }

    for (int t = 0; t < NT; ++t) {
        const int cur = t & 1;

        float4v accS[2] = {{0,0,0,0},{0,0,0,0}};
        qk(cur, accS);

        // normalized p -> per-wave fp16 P buffer (C layout write)
        #pragma unroll
        for (int sub = 0; sub < 2; ++sub)
            #pragma unroll
            for (int r = 0; r < 4; ++r) {
                float p = __expf(accS[sub][r] * SCALE) * invl[r];
                pw[(g * 4 + r) * PSTRIDE + sub * 16 + c16] = (_Float16)p;
            }
        LGKM0();

        // read back in A layout: row c16, halves g*8..+7 (16B aligned)
        half8 ph = *(const half8*)&pw[c16 * PSTRIDE + g * 8];
        float pf[8];
        #pragma unroll
        for (int j = 0; j < 8; ++j) pf[j] = (float)ph[j];

        // vectorized attn store (never waited on — no vmcnt drain in loop)
        float* as_ = &Ah[(size_t)(qrow0 + c16) * Sc + t * KT + g * 8];
        *(float4v*)as_       = (float4v){pf[0], pf[1], pf[2], pf[3]};
        *(float4v*)(as_ + 4) = (float4v){pf[4], pf[5], pf[6], pf[7]};

        // blend with prefetched M, convert to fp16 A-fragment
        half8 ap;
        #pragma unroll
        for (int j = 0; j < 4; ++j) {
            ap[j]     = (_Float16)(0.7f * pf[j]     + 0.3f * m0[j]);
            ap[4 + j] = (_Float16)(0.7f * pf[4 + j] + 0.3f * m1[j]);
        }
        if (t + 1 < NT) loadM(t + 1);

        // ---- PV: tr-reads pipelined 3-pairs-deep, counted lgkm ----
        LGKM0();   // zero the lgkm baseline for counted waits
        const unsigned int vb = vbase0 + (unsigned int)(cur * (KT * Dc * 2));
        TRI(0) TRI(1)
        TRI(2) PVM(0, 4)
        TRI(3) PVM(1, 4)
        TRI(4) PVM(2, 4)
        TRI(5) PVM(3, 4)
        TRI(6) PVM(4, 4)
        TRI(7) PVM(5, 4)
        PVM(6, 2)
        PVM(7, 0)

        // stage next tile into the other buffer; issue loads for t+2
        if (t + 1 < NT) {
            writeK(cur ^ 1); writeV(cur ^ 1);
            if (t + 2 < NT) { loadK(t + 2); loadV(t + 2); }
        }
        LGKM0(); SBAR();
    }

    // ================= epilogue: context =================
    #pragma unroll
    for (int d = 0; d < 8; ++d)
        #pragma unroll
        for (int r = 0; r < 4; ++r)
            Ch[(size_t)(qrow0 + g * 4 + r) * Dc + d * 16 + c16] = accC[d][r];
}

extern "C" void kernel_launch(void* const* d_in, const int* in_sizes, int n_in,
                              void* d_out, int out_size, void* d_ws, size_t ws_size,
                              hipStream_t stream) {
    const float* Q = (const float*)d_in[0];
    const float* K = (const float*)d_in[1];
    const float* V = (const float*)d_in[2];
    const float* M = (const float*)d_in[4];   // d_in[3] = attn_mask (unused)
    float* outC = (float*)d_out;
    float* outA = outC + (size_t)Bc * Hc * Sc * Dc;

    const int grid = Bc * Hc * (Sc / BQ);  // 1024
    sdpa_kernel<<<dim3(grid), dim3(256), 0, stream>>>(Q, K, V, M, outC, outA);
}